// Round 1
// baseline (7126.908 us; speedup 1.0000x reference)
//
#include <hip/hip_runtime.h>

#define N_NODES 30000
#define N_EDGES 300000
#define NUM_GRAPHS 512
#define HID 600
#define IN_FEATS 9
#define NUM_TASKS 128

// ---------------- CSR build ----------------

__global__ void k_hist(const int* __restrict__ keys, int* __restrict__ counts, int n) {
  int i = blockIdx.x * blockDim.x + threadIdx.x;
  if (i < n) atomicAdd(&counts[keys[i]], 1);
}

// single-block exclusive scan; out has n+1 entries (out[n] = total)
__global__ void k_exscan(const int* __restrict__ in, int* __restrict__ out, int n) {
  __shared__ int buf[1024];
  __shared__ int carry_s;
  int tid = threadIdx.x;
  if (tid == 0) carry_s = 0;
  __syncthreads();
  for (int base = 0; base <= n; base += 1024) {
    int i = base + tid;
    int v = (i < n) ? in[i] : 0;
    buf[tid] = v;
    __syncthreads();
    for (int off = 1; off < 1024; off <<= 1) {
      int t = (tid >= off) ? buf[tid - off] : 0;
      __syncthreads();
      buf[tid] += t;
      __syncthreads();
    }
    int incl = buf[tid];
    int c = carry_s;
    if (i <= n) out[i] = c + incl - v;
    __syncthreads();
    if (tid == 1023) carry_s = c + incl;
    __syncthreads();
  }
}

__global__ void k_copy_int(const int* __restrict__ in, int* __restrict__ out, int n) {
  int i = blockIdx.x * blockDim.x + threadIdx.x;
  if (i < n) out[i] = in[i];
}

__global__ void k_scatter(const int* __restrict__ src, const int* __restrict__ dst,
                          int* __restrict__ cursor, int* __restrict__ edge_src, int E) {
  int e = blockIdx.x * blockDim.x + threadIdx.x;
  if (e < E) {
    int pos = atomicAdd(&cursor[dst[e]], 1);
    edge_src[pos] = src[e];
  }
}

// ---------------- aggregation: z[i] = h[i] + sum_{e: dst==i} h[src_e] ----------------

__global__ __launch_bounds__(256) void k_aggregate(
    const float* __restrict__ h, const int* __restrict__ ptr,
    const int* __restrict__ esrc, float* __restrict__ z, int dim) {
  int node = blockIdx.x;
  int beg = ptr[node], end = ptr[node + 1];
  int d0 = threadIdx.x, d1 = threadIdx.x + 256, d2 = threadIdx.x + 512;
  const float* hn = h + (size_t)node * dim;
  float a0 = 0.f, a1 = 0.f, a2 = 0.f;
  if (d0 < dim) a0 = hn[d0];
  if (d1 < dim) a1 = hn[d1];
  if (d2 < dim) a2 = hn[d2];
  for (int e = beg; e < end; ++e) {
    const float* hs = h + (size_t)esrc[e] * dim;
    if (d0 < dim) a0 += hs[d0];
    if (d1 < dim) a1 += hs[d1];
    if (d2 < dim) a2 += hs[d2];
  }
  float* zn = z + (size_t)node * dim;
  if (d0 < dim) zn[d0] = a0;
  if (d1 < dim) zn[d1] = a1;
  if (d2 < dim) zn[d2] = a2;
}

// ---------------- pool: feats[g] = sum_{i in [gptr[g],gptr[g+1])} h[i] ----------------

__global__ __launch_bounds__(256) void k_pool(
    const float* __restrict__ h, const int* __restrict__ gptr,
    float* __restrict__ feats, int dim) {
  int g = blockIdx.x;
  int beg = gptr[g], end = gptr[g + 1];
  int d0 = threadIdx.x, d1 = threadIdx.x + 256, d2 = threadIdx.x + 512;
  float a0 = 0.f, a1 = 0.f, a2 = 0.f;
  for (int i = beg; i < end; ++i) {
    const float* hi = h + (size_t)i * dim;
    if (d0 < dim) a0 += hi[d0];
    if (d1 < dim) a1 += hi[d1];
    if (d2 < dim) a2 += hi[d2];
  }
  float* fg = feats + (size_t)g * dim;
  if (d0 < dim) fg[d0] = a0;
  if (d1 < dim) fg[d1] = a1;
  if (d2 < dim) fg[d2] = a2;
}

// ---------------- fp32 tiled GEMM: C = act(A[M,K] @ W[K,N] + bias) ----------------

#define TS 64
#define BKK 16

__global__ __launch_bounds__(256) void k_gemm(
    const float* __restrict__ A, const float* __restrict__ W,
    const float* __restrict__ bias, float* __restrict__ C,
    int M, int K, int N, int relu) {
  __shared__ float As[BKK][TS + 1];  // [k][m]
  __shared__ float Ws[BKK][TS + 1];  // [k][n]
  int t = threadIdx.x;
  int tx = t % 16, ty = t / 16;
  int m0 = blockIdx.x * TS, n0 = blockIdx.y * TS;
  float acc[4][4] = {{0.f}};
  for (int k0 = 0; k0 < K; k0 += BKK) {
    for (int i = 0; i < 4; ++i) {
      int idx = t + i * 256;     // 0..1023
      int k = idx % BKK;         // 0..15
      int m = idx / BKK;         // 0..63
      int gm = m0 + m, gk = k0 + k;
      float v = 0.f;
      if (gm < M && gk < K) v = A[gm * K + gk];
      As[k][m] = v;
    }
    for (int i = 0; i < 4; ++i) {
      int idx = t + i * 256;
      int n = idx % TS;          // 0..63
      int k = idx / TS;          // 0..15
      int gk = k0 + k, gn = n0 + n;
      float v = 0.f;
      if (gk < K && gn < N) v = W[gk * N + gn];
      Ws[k][n] = v;
    }
    __syncthreads();
#pragma unroll
    for (int k = 0; k < BKK; ++k) {
      float a[4], w[4];
#pragma unroll
      for (int i = 0; i < 4; ++i) a[i] = As[k][ty * 4 + i];
#pragma unroll
      for (int j = 0; j < 4; ++j) w[j] = Ws[k][tx * 4 + j];
#pragma unroll
      for (int i = 0; i < 4; ++i)
#pragma unroll
        for (int j = 0; j < 4; ++j) acc[i][j] += a[i] * w[j];
    }
    __syncthreads();
  }
#pragma unroll
  for (int i = 0; i < 4; ++i) {
    int gm = m0 + ty * 4 + i;
    if (gm >= M) continue;
#pragma unroll
    for (int j = 0; j < 4; ++j) {
      int gn = n0 + tx * 4 + j;
      if (gn >= N) continue;
      float v = acc[i][j] + bias[gn];
      if (relu) v = fmaxf(v, 0.f);
      C[gm * N + gn] = v;
    }
  }
}

// ---------------- host ----------------

static inline dim3 gemm_grid(int M, int N) {
  return dim3((M + TS - 1) / TS, (N + TS - 1) / TS);
}

extern "C" void kernel_launch(void* const* d_in, const int* in_sizes, int n_in,
                              void* d_out, int out_size, void* d_ws, size_t ws_size,
                              hipStream_t stream) {
  const float* x      = (const float*)d_in[0];
  const int*   ei     = (const int*)d_in[1];   // [2, E]: row0 = src, row1 = dst
  const int*   batch  = (const int*)d_in[2];
  const float* w1_0   = (const float*)d_in[3];
  const float* b1_0   = (const float*)d_in[4];
  const float* w2_0   = (const float*)d_in[5];
  const float* b2_0   = (const float*)d_in[6];
  const float* w1_r   = (const float*)d_in[7];
  const float* b1_r   = (const float*)d_in[8];
  const float* w2_r   = (const float*)d_in[9];
  const float* b2_r   = (const float*)d_in[10];
  const float* cw1    = (const float*)d_in[11];
  const float* cb1    = (const float*)d_in[12];
  const float* cw2    = (const float*)d_in[13];
  const float* cb2    = (const float*)d_in[14];
  const float* cw3    = (const float*)d_in[15];
  const float* cb3    = (const float*)d_in[16];
  float* out = (float*)d_out;

  const int* e_src = ei;
  const int* e_dst = ei + N_EDGES;

  // workspace layout
  float* bufA = (float*)d_ws;               // 18,000,000 floats
  float* bufB = bufA + (size_t)N_NODES * HID;
  float* bufC = bufB + (size_t)N_NODES * HID;
  float* feats = bufC + (size_t)N_NODES * HID;       // 512*600
  float* z1 = feats + (size_t)NUM_GRAPHS * HID;      // 512*256
  float* z2 = z1 + (size_t)NUM_GRAPHS * 256;         // 512*256
  int* row_ptr  = (int*)(z2 + (size_t)NUM_GRAPHS * 256);  // N_NODES+1
  int* counts   = row_ptr + (N_NODES + 1);                // N_NODES (also cursor)
  int* edge_src = counts + N_NODES;                       // N_EDGES
  int* gptr     = edge_src + N_EDGES;                     // NUM_GRAPHS+1
  int* gcnt     = gptr + (NUM_GRAPHS + 1);                // NUM_GRAPHS

  // ---- CSR by destination ----
  hipMemsetAsync(counts, 0, N_NODES * sizeof(int), stream);
  k_hist<<<(N_EDGES + 255) / 256, 256, 0, stream>>>(e_dst, counts, N_EDGES);
  k_exscan<<<1, 1024, 0, stream>>>(counts, row_ptr, N_NODES);
  k_copy_int<<<(N_NODES + 255) / 256, 256, 0, stream>>>(row_ptr, counts, N_NODES);
  k_scatter<<<(N_EDGES + 255) / 256, 256, 0, stream>>>(e_src, e_dst, counts, edge_src, N_EDGES);

  // ---- graph ptr (batch_ind is sorted) ----
  hipMemsetAsync(gcnt, 0, NUM_GRAPHS * sizeof(int), stream);
  k_hist<<<(N_NODES + 255) / 256, 256, 0, stream>>>(batch, gcnt, N_NODES);
  k_exscan<<<1, 1024, 0, stream>>>(gcnt, gptr, NUM_GRAPHS);

  // ---- layer 0 (IN_FEATS -> HID) ----
  k_aggregate<<<N_NODES, 256, 0, stream>>>(x, row_ptr, edge_src, bufB, IN_FEATS);
  k_gemm<<<gemm_grid(N_NODES, HID), 256, 0, stream>>>(bufB, w1_0, b1_0, bufC,
                                                      N_NODES, IN_FEATS, HID, 1);
  k_gemm<<<gemm_grid(N_NODES, HID), 256, 0, stream>>>(bufC, w2_0, b2_0, bufA,
                                                      N_NODES, HID, HID, 1);  // + outer relu

  // ---- layers 1..4 ----
  float* h = bufA;
  float* zb = bufB;
  float* tb = bufC;
  for (int i = 0; i < 4; ++i) {
    const float* w1 = w1_r + (size_t)i * HID * HID;
    const float* b1 = b1_r + (size_t)i * HID;
    const float* w2 = w2_r + (size_t)i * HID * HID;
    const float* b2 = b2_r + (size_t)i * HID;
    k_aggregate<<<N_NODES, 256, 0, stream>>>(h, row_ptr, edge_src, zb, HID);
    k_gemm<<<gemm_grid(N_NODES, HID), 256, 0, stream>>>(zb, w1, b1, tb,
                                                        N_NODES, HID, HID, 1);
    k_gemm<<<gemm_grid(N_NODES, HID), 256, 0, stream>>>(tb, w2, b2, zb,
                                                        N_NODES, HID, HID, (i < 3) ? 1 : 0);
    float* tmp = h; h = zb; zb = tmp;
  }

  // ---- pool + classifier ----
  k_pool<<<NUM_GRAPHS, 256, 0, stream>>>(h, gptr, feats, HID);
  k_gemm<<<gemm_grid(NUM_GRAPHS, 256), 256, 0, stream>>>(feats, cw1, cb1, z1,
                                                         NUM_GRAPHS, HID, 256, 1);
  k_gemm<<<gemm_grid(NUM_GRAPHS, 256), 256, 0, stream>>>(z1, cw2, cb2, z2,
                                                         NUM_GRAPHS, 256, 256, 1);
  k_gemm<<<gemm_grid(NUM_GRAPHS, NUM_TASKS), 256, 0, stream>>>(z2, cw3, cb3, out,
                                                               NUM_GRAPHS, 256, NUM_TASKS, 0);
}

// Round 2
// 1109.185 us; speedup vs baseline: 6.4254x; 6.4254x over previous
//
#include <hip/hip_runtime.h>

#define N_NODES 30000
#define N_EDGES 300000
#define NUM_GRAPHS 512
#define HID 600
#define IN_FEATS 9
#define NUM_TASKS 128

#define MPAD 30080          // 235 * 128
#define HPAD 640            // 600 padded
#define K0PAD 32            // layer-0 K pad

typedef __attribute__((ext_vector_type(4))) float f32x4;
typedef __attribute__((ext_vector_type(8))) short bf16x8;

// ---------------- bf16 helpers ----------------

__device__ __forceinline__ float bflo(unsigned int v) {
  union { unsigned int u; float f; } c; c.u = v << 16; return c.f;
}
__device__ __forceinline__ float bfhi(unsigned int v) {
  union { unsigned int u; float f; } c; c.u = v & 0xffff0000u; return c.f;
}
__device__ __forceinline__ unsigned short f2bf(float f) {
  union { float f; unsigned int u; } c; c.f = f;
  unsigned int u = c.u;
  return (unsigned short)((u + 0x7fffu + ((u >> 16) & 1u)) >> 16);
}
__device__ __forceinline__ unsigned int pack2(float a, float b) {
  return (unsigned int)f2bf(a) | ((unsigned int)f2bf(b) << 16);
}

// ---------------- CSR build ----------------

__global__ void k_hist(const int* __restrict__ keys, int* __restrict__ counts, int n) {
  int i = blockIdx.x * blockDim.x + threadIdx.x;
  if (i < n) atomicAdd(&counts[keys[i]], 1);
}

__global__ void k_exscan(const int* __restrict__ in, int* __restrict__ out, int n) {
  __shared__ int buf[1024];
  __shared__ int carry_s;
  int tid = threadIdx.x;
  if (tid == 0) carry_s = 0;
  __syncthreads();
  for (int base = 0; base <= n; base += 1024) {
    int i = base + tid;
    int v = (i < n) ? in[i] : 0;
    buf[tid] = v;
    __syncthreads();
    for (int off = 1; off < 1024; off <<= 1) {
      int t = (tid >= off) ? buf[tid - off] : 0;
      __syncthreads();
      buf[tid] += t;
      __syncthreads();
    }
    int incl = buf[tid];
    int c = carry_s;
    if (i <= n) out[i] = c + incl - v;
    __syncthreads();
    if (tid == 1023) carry_s = c + incl;
    __syncthreads();
  }
}

__global__ void k_copy_int(const int* __restrict__ in, int* __restrict__ out, int n) {
  int i = blockIdx.x * blockDim.x + threadIdx.x;
  if (i < n) out[i] = in[i];
}

__global__ void k_scatter(const int* __restrict__ src, const int* __restrict__ dst,
                          int* __restrict__ cursor, int* __restrict__ edge_src, int E) {
  int e = blockIdx.x * blockDim.x + threadIdx.x;
  if (e < E) {
    int pos = atomicAdd(&cursor[dst[e]], 1);
    edge_src[pos] = src[e];
  }
}

// ---------------- conversions ----------------

// Wt[n][k] (NP x KP) bf16 <- W[k][n] (K x N) f32, zero-padded
__global__ void k_wt(const float* __restrict__ W, unsigned short* __restrict__ Wt,
                     int K, int N, int KP, int NP) {
  int idx = blockIdx.x * 256 + threadIdx.x;
  if (idx >= NP * KP) return;
  int n = idx / KP, k = idx % KP;
  float v = (n < N && k < K) ? W[(size_t)k * N + n] : 0.f;
  Wt[idx] = f2bf(v);
}

__global__ void k_biaspad(const float* __restrict__ src, float* __restrict__ dst, int n) {
  int i = blockIdx.x * 256 + threadIdx.x;
  if (i < HPAD) dst[i] = (i < n) ? src[i] : 0.f;
}

// x [30000][9] f32 -> xb [30080][32] bf16, zero-padded
__global__ void k_xconv(const float* __restrict__ x, unsigned short* __restrict__ xb) {
  int idx = blockIdx.x * 256 + threadIdx.x;
  if (idx >= MPAD * K0PAD) return;
  int m = idx >> 5, k = idx & 31;
  float v = (m < N_NODES && k < IN_FEATS) ? x[(size_t)m * IN_FEATS + k] : 0.f;
  xb[idx] = f2bf(v);
}

// ---------------- aggregation (bf16): z[i] = h[i] + sum_{e:dst=i} h[src] ----------------
// wave per node; lane handles uints lane + i*64; U = cols/2 uints per row

template <int U>
__global__ __launch_bounds__(256) void k_agg_bf16(
    const unsigned int* __restrict__ h, const int* __restrict__ ptr,
    const int* __restrict__ esrc, unsigned int* __restrict__ z, int n_nodes) {
  int wave = threadIdx.x >> 6, lane = threadIdx.x & 63;
  int node = blockIdx.x * 4 + wave;
  if (node >= n_nodes) return;
  int beg = ptr[node], end = ptr[node + 1];
  const unsigned int* hn = h + (size_t)node * U;
  float a0[5], a1[5];
#pragma unroll
  for (int i = 0; i < 5; ++i) {
    int u = lane + i * 64;
    if (u < U) { unsigned int v = hn[u]; a0[i] = bflo(v); a1[i] = bfhi(v); }
    else { a0[i] = 0.f; a1[i] = 0.f; }
  }
  for (int e = beg; e < end; ++e) {
    const unsigned int* hs = h + (size_t)esrc[e] * U;
#pragma unroll
    for (int i = 0; i < 5; ++i) {
      int u = lane + i * 64;
      if (u < U) { unsigned int v = hs[u]; a0[i] += bflo(v); a1[i] += bfhi(v); }
    }
  }
  unsigned int* zn = z + (size_t)node * U;
#pragma unroll
  for (int i = 0; i < 5; ++i) {
    int u = lane + i * 64;
    if (u < U) zn[u] = pack2(a0[i], a1[i]);
  }
}

// ---------------- pool: feats[g] (f32) = sum over nodes of h (bf16) ----------------

__global__ __launch_bounds__(256) void k_pool_bf16(
    const unsigned int* __restrict__ h, const int* __restrict__ gptr,
    float* __restrict__ feats) {
  const int U = HPAD / 2;  // 320
  int wave = threadIdx.x >> 6, lane = threadIdx.x & 63;
  int g = blockIdx.x * 4 + wave;
  int beg = gptr[g], end = gptr[g + 1];
  float a0[5] = {0.f, 0.f, 0.f, 0.f, 0.f}, a1[5] = {0.f, 0.f, 0.f, 0.f, 0.f};
  for (int i = beg; i < end; ++i) {
    const unsigned int* hi = h + (size_t)i * U;
#pragma unroll
    for (int j = 0; j < 5; ++j) {
      unsigned int v = hi[lane + j * 64];
      a0[j] += bflo(v); a1[j] += bfhi(v);
    }
  }
  float* fg = feats + (size_t)g * HPAD;
#pragma unroll
  for (int j = 0; j < 5; ++j) {
    int u = lane + j * 64;
    fg[2 * u] = a0[j];
    fg[2 * u + 1] = a1[j];
  }
}

// ---------------- bf16 MFMA GEMM: C[m][n] = act(sum_k A[m][k]*Bt[n][k] + bias[n]) ----------------
// 128x128 tile, BK=32, 4 waves, m97 2-barrier structure, global_load_lds w16.

__global__ __launch_bounds__(256) void k_mgemm(
    const unsigned short* __restrict__ A, const unsigned short* __restrict__ Bt,
    const float* __restrict__ bias, unsigned short* __restrict__ C,
    int lda, int ldb, int K, int relu) {
  __shared__ unsigned short As[128 * 32];
  __shared__ unsigned short Bs[128 * 32];
  int t = threadIdx.x;
  int lane = t & 63, wave = t >> 6;
  int m0 = blockIdx.x * 128, n0 = blockIdx.y * 128;
  int wm = (wave >> 1) * 64, wn = (wave & 1) * 64;

  f32x4 acc[4][4] = {};

  int off0 = t * 8, off1 = t * 8 + 2048;   // elems within 128x32 tile
  int rm0 = off0 >> 5, rk0 = off0 & 31;    // row, k within tile
  int rm1 = off1 >> 5, rk1 = off1 & 31;

  for (int k0 = 0; k0 < K; k0 += 32) {
    __builtin_amdgcn_global_load_lds(
        (const __attribute__((address_space(1))) unsigned int*)(A + (size_t)(m0 + rm0) * lda + k0 + rk0),
        (__attribute__((address_space(3))) unsigned int*)(As + off0), 16, 0, 0);
    __builtin_amdgcn_global_load_lds(
        (const __attribute__((address_space(1))) unsigned int*)(A + (size_t)(m0 + rm1) * lda + k0 + rk1),
        (__attribute__((address_space(3))) unsigned int*)(As + off1), 16, 0, 0);
    __builtin_amdgcn_global_load_lds(
        (const __attribute__((address_space(1))) unsigned int*)(Bt + (size_t)(n0 + rm0) * ldb + k0 + rk0),
        (__attribute__((address_space(3))) unsigned int*)(Bs + off0), 16, 0, 0);
    __builtin_amdgcn_global_load_lds(
        (const __attribute__((address_space(1))) unsigned int*)(Bt + (size_t)(n0 + rm1) * ldb + k0 + rk1),
        (__attribute__((address_space(3))) unsigned int*)(Bs + off1), 16, 0, 0);
    __syncthreads();

    int kk = (lane >> 4) * 8;
    int ra = wm + (lane & 15);
    int rb = wn + (lane & 15);
    bf16x8 a[4], b[4];
#pragma unroll
    for (int i = 0; i < 4; ++i)
      a[i] = *(const bf16x8*)(As + (ra + i * 16) * 32 + kk);
#pragma unroll
    for (int j = 0; j < 4; ++j)
      b[j] = *(const bf16x8*)(Bs + (rb + j * 16) * 32 + kk);
#pragma unroll
    for (int i = 0; i < 4; ++i)
#pragma unroll
      for (int j = 0; j < 4; ++j)
        acc[i][j] = __builtin_amdgcn_mfma_f32_16x16x32_bf16(a[i], b[j], acc[i][j], 0, 0, 0);
    __syncthreads();
  }

  int col = lane & 15, r4 = (lane >> 4) * 4;
#pragma unroll
  for (int j = 0; j < 4; ++j) {
    int n = n0 + wn + j * 16 + col;
    float bv = bias[n];
#pragma unroll
    for (int i = 0; i < 4; ++i) {
      int mb = m0 + wm + i * 16 + r4;
#pragma unroll
      for (int r = 0; r < 4; ++r) {
        float v = acc[i][j][r] + bv;
        if (relu) v = fmaxf(v, 0.f);
        C[(size_t)(mb + r) * HPAD + n] = f2bf(v);
      }
    }
  }
}

// ---------------- fp32 tiled GEMM (classifier only) ----------------

#define TS 64
#define BKK 16

__global__ __launch_bounds__(256) void k_gemm(
    const float* __restrict__ A, const float* __restrict__ W,
    const float* __restrict__ bias, float* __restrict__ C,
    int lda, int M, int K, int N, int relu) {
  __shared__ float As[BKK][TS + 1];
  __shared__ float Ws[BKK][TS + 1];
  int t = threadIdx.x;
  int tx = t % 16, ty = t / 16;
  int m0 = blockIdx.x * TS, n0 = blockIdx.y * TS;
  float acc[4][4] = {{0.f}};
  for (int k0 = 0; k0 < K; k0 += BKK) {
    for (int i = 0; i < 4; ++i) {
      int idx = t + i * 256;
      int k = idx % BKK;
      int m = idx / BKK;
      int gm = m0 + m, gk = k0 + k;
      float v = 0.f;
      if (gm < M && gk < K) v = A[(size_t)gm * lda + gk];
      As[k][m] = v;
    }
    for (int i = 0; i < 4; ++i) {
      int idx = t + i * 256;
      int n = idx % TS;
      int k = idx / TS;
      int gk = k0 + k, gn = n0 + n;
      float v = 0.f;
      if (gk < K && gn < N) v = W[(size_t)gk * N + gn];
      Ws[k][n] = v;
    }
    __syncthreads();
#pragma unroll
    for (int k = 0; k < BKK; ++k) {
      float a[4], w[4];
#pragma unroll
      for (int i = 0; i < 4; ++i) a[i] = As[k][ty * 4 + i];
#pragma unroll
      for (int j = 0; j < 4; ++j) w[j] = Ws[k][tx * 4 + j];
#pragma unroll
      for (int i = 0; i < 4; ++i)
#pragma unroll
        for (int j = 0; j < 4; ++j) acc[i][j] += a[i] * w[j];
    }
    __syncthreads();
  }
#pragma unroll
  for (int i = 0; i < 4; ++i) {
    int gm = m0 + ty * 4 + i;
    if (gm >= M) continue;
#pragma unroll
    for (int j = 0; j < 4; ++j) {
      int gn = n0 + tx * 4 + j;
      if (gn >= N) continue;
      float v = acc[i][j] + bias[gn];
      if (relu) v = fmaxf(v, 0.f);
      C[(size_t)gm * N + gn] = v;
    }
  }
}

// ---------------- host ----------------

extern "C" void kernel_launch(void* const* d_in, const int* in_sizes, int n_in,
                              void* d_out, int out_size, void* d_ws, size_t ws_size,
                              hipStream_t stream) {
  const float* x      = (const float*)d_in[0];
  const int*   ei     = (const int*)d_in[1];
  const int*   batch  = (const int*)d_in[2];
  const float* w1_0   = (const float*)d_in[3];
  const float* b1_0   = (const float*)d_in[4];
  const float* w2_0   = (const float*)d_in[5];
  const float* b2_0   = (const float*)d_in[6];
  const float* w1_r   = (const float*)d_in[7];
  const float* b1_r   = (const float*)d_in[8];
  const float* w2_r   = (const float*)d_in[9];
  const float* b2_r   = (const float*)d_in[10];
  const float* cw1    = (const float*)d_in[11];
  const float* cb1    = (const float*)d_in[12];
  const float* cw2    = (const float*)d_in[13];
  const float* cb2    = (const float*)d_in[14];
  const float* cw3    = (const float*)d_in[15];
  const float* cb3    = (const float*)d_in[16];
  float* out = (float*)d_out;

  const int* e_src = ei;
  const int* e_dst = ei + N_EDGES;

  const size_t HBUF = (size_t)MPAD * HPAD;      // 19,251,200 elems
  const size_t ZBUF = (size_t)MPAD * K0PAD;     // 962,560
  const size_t WT   = (size_t)HPAD * HPAD;      // 409,600

  unsigned short* hA  = (unsigned short*)d_ws;
  unsigned short* hB  = hA + HBUF;
  unsigned short* hC  = hB + HBUF;
  unsigned short* z0  = hC + HBUF;
  unsigned short* xb  = z0 + ZBUF;
  unsigned short* wt0 = xb + ZBUF;              // [640][32]
  unsigned short* wts = wt0 + (size_t)HPAD * K0PAD;  // 9 x [640][640]
  float* biases = (float*)(wts + 9 * WT);       // [10][640]
  float* feats  = biases + 10 * HPAD;           // [512][640]
  float* zc1    = feats + (size_t)NUM_GRAPHS * HPAD;
  float* zc2    = zc1 + (size_t)NUM_GRAPHS * 256;
  int* row_ptr  = (int*)(zc2 + (size_t)NUM_GRAPHS * 256);
  int* counts   = row_ptr + (N_NODES + 1);
  int* edge_src = counts + N_NODES;
  int* gptr     = edge_src + N_EDGES;
  int* gcnt     = gptr + (NUM_GRAPHS + 1);

  // ---- weight / bias / input conversions ----
  k_wt<<<(HPAD * K0PAD + 255) / 256, 256, 0, stream>>>(w1_0, wt0, IN_FEATS, HID, K0PAD, HPAD);
  k_wt<<<(HPAD * HPAD + 255) / 256, 256, 0, stream>>>(w2_0, wts, HID, HID, HPAD, HPAD);
  for (int i = 0; i < 4; ++i) {
    k_wt<<<(HPAD * HPAD + 255) / 256, 256, 0, stream>>>(
        w1_r + (size_t)i * HID * HID, wts + (1 + i) * WT, HID, HID, HPAD, HPAD);
    k_wt<<<(HPAD * HPAD + 255) / 256, 256, 0, stream>>>(
        w2_r + (size_t)i * HID * HID, wts + (5 + i) * WT, HID, HID, HPAD, HPAD);
  }
  k_biaspad<<<3, 256, 0, stream>>>(b1_0, biases + 0 * HPAD, HID);
  k_biaspad<<<3, 256, 0, stream>>>(b2_0, biases + 1 * HPAD, HID);
  for (int i = 0; i < 4; ++i) {
    k_biaspad<<<3, 256, 0, stream>>>(b1_r + (size_t)i * HID, biases + (2 + i) * HPAD, HID);
    k_biaspad<<<3, 256, 0, stream>>>(b2_r + (size_t)i * HID, biases + (6 + i) * HPAD, HID);
  }
  k_xconv<<<(MPAD * K0PAD + 255) / 256, 256, 0, stream>>>(x, xb);

  // ---- CSR by destination ----
  hipMemsetAsync(counts, 0, N_NODES * sizeof(int), stream);
  k_hist<<<(N_EDGES + 255) / 256, 256, 0, stream>>>(e_dst, counts, N_EDGES);
  k_exscan<<<1, 1024, 0, stream>>>(counts, row_ptr, N_NODES);
  k_copy_int<<<(N_NODES + 255) / 256, 256, 0, stream>>>(row_ptr, counts, N_NODES);
  k_scatter<<<(N_EDGES + 255) / 256, 256, 0, stream>>>(e_src, e_dst, counts, edge_src, N_EDGES);

  hipMemsetAsync(gcnt, 0, NUM_GRAPHS * sizeof(int), stream);
  k_hist<<<(N_NODES + 255) / 256, 256, 0, stream>>>(batch, gcnt, N_NODES);
  k_exscan<<<1, 1024, 0, stream>>>(gcnt, gptr, NUM_GRAPHS);

  dim3 ggrid(MPAD / 128, HPAD / 128);  // 235 x 5

  // ---- layer 0 ----
  k_agg_bf16<K0PAD / 2><<<(N_NODES + 3) / 4, 256, 0, stream>>>(
      (const unsigned int*)xb, row_ptr, edge_src, (unsigned int*)z0, N_NODES);
  k_mgemm<<<ggrid, 256, 0, stream>>>(z0, wt0, biases + 0 * HPAD, hC, K0PAD, K0PAD, K0PAD, 1);
  k_mgemm<<<ggrid, 256, 0, stream>>>(hC, wts, biases + 1 * HPAD, hA, HPAD, HPAD, HPAD, 1);

  // ---- layers 1..4 ----
  unsigned short* h = hA;
  unsigned short* z = hB;
  unsigned short* tb = hC;
  for (int i = 0; i < 4; ++i) {
    k_agg_bf16<HPAD / 2><<<(N_NODES + 3) / 4, 256, 0, stream>>>(
        (const unsigned int*)h, row_ptr, edge_src, (unsigned int*)z, N_NODES);
    k_mgemm<<<ggrid, 256, 0, stream>>>(z, wts + (1 + i) * WT, biases + (2 + i) * HPAD, tb,
                                       HPAD, HPAD, HPAD, 1);
    k_mgemm<<<ggrid, 256, 0, stream>>>(tb, wts + (5 + i) * WT, biases + (6 + i) * HPAD, z,
                                       HPAD, HPAD, HPAD, (i < 3) ? 1 : 0);
    unsigned short* tmp = h; h = z; z = tmp;
  }

  // ---- pool + classifier ----
  k_pool_bf16<<<NUM_GRAPHS / 4, 256, 0, stream>>>((const unsigned int*)h, gptr, feats);
  k_gemm<<<dim3(8, 4), 256, 0, stream>>>(feats, cw1, cb1, zc1, HPAD, NUM_GRAPHS, HID, 256, 1);
  k_gemm<<<dim3(8, 4), 256, 0, stream>>>(zc1, cw2, cb2, zc2, 256, NUM_GRAPHS, 256, 256, 1);
  k_gemm<<<dim3(8, 2), 256, 0, stream>>>(zc2, cw3, cb3, out, 256, NUM_GRAPHS, 256, NUM_TASKS, 0);
}

// Round 3
// 925.983 us; speedup vs baseline: 7.6966x; 1.1978x over previous
//
#include <hip/hip_runtime.h>

#define N_NODES 30000
#define N_EDGES 300000
#define NUM_GRAPHS 512
#define HID 600
#define IN_FEATS 9
#define NUM_TASKS 128

#define MPAD 30080          // 235 * 128
#define HPAD 640            // 600 padded
#define K0PAD 32            // layer-0 K pad

typedef __attribute__((ext_vector_type(4))) float f32x4;
typedef __attribute__((ext_vector_type(8))) short bf16x8;

// ---------------- bf16 helpers ----------------

__device__ __forceinline__ float bflo(unsigned int v) {
  union { unsigned int u; float f; } c; c.u = v << 16; return c.f;
}
__device__ __forceinline__ float bfhi(unsigned int v) {
  union { unsigned int u; float f; } c; c.u = v & 0xffff0000u; return c.f;
}
__device__ __forceinline__ unsigned short f2bf(float f) {
  union { float f; unsigned int u; } c; c.f = f;
  unsigned int u = c.u;
  return (unsigned short)((u + 0x7fffu + ((u >> 16) & 1u)) >> 16);
}
__device__ __forceinline__ unsigned int pack2(float a, float b) {
  return (unsigned int)f2bf(a) | ((unsigned int)f2bf(b) << 16);
}

// ---------------- CSR build ----------------

__global__ void k_hist(const int* __restrict__ keys, int* __restrict__ counts, int n) {
  int i = blockIdx.x * blockDim.x + threadIdx.x;
  if (i < n) atomicAdd(&counts[keys[i]], 1);
}

// chunk-per-thread exclusive scan, single block of 1024; out[n] = total
__global__ __launch_bounds__(1024) void k_exscan(const int* __restrict__ in,
                                                 int* __restrict__ out, int n) {
  __shared__ int buf[1024];
  int tid = threadIdx.x;
  int CH = (n + 1023) / 1024;
  int base = tid * CH;
  int s = 0;
  for (int j = 0; j < CH; ++j) {
    int i = base + j;
    if (i < n) s += in[i];
  }
  buf[tid] = s;
  __syncthreads();
  for (int off = 1; off < 1024; off <<= 1) {
    int t = (tid >= off) ? buf[tid - off] : 0;
    __syncthreads();
    buf[tid] += t;
    __syncthreads();
  }
  int pre = (tid == 0) ? 0 : buf[tid - 1];
  for (int j = 0; j < CH; ++j) {
    int i = base + j;
    if (i <= n) out[i] = pre;
    if (i < n) pre += in[i];
  }
  // thread owning index n already wrote out[n]=total above when i==n
}

__global__ void k_copy_int(const int* __restrict__ in, int* __restrict__ out, int n) {
  int i = blockIdx.x * blockDim.x + threadIdx.x;
  if (i < n) out[i] = in[i];
}

__global__ void k_scatter(const int* __restrict__ src, const int* __restrict__ dst,
                          int* __restrict__ cursor, int* __restrict__ edge_src, int E) {
  int e = blockIdx.x * blockDim.x + threadIdx.x;
  if (e < E) {
    int pos = atomicAdd(&cursor[dst[e]], 1);
    edge_src[pos] = src[e];
  }
}

// ---------------- fused conversions ----------------

// wt0 [HPAD][K0PAD] <- w1_0 [9][600]; wts[w] [HPAD][HPAD] <- {w2_0, w1_r[0..3], w2_r[0..3]}
__global__ void k_wt_all(const float* __restrict__ w1_0, const float* __restrict__ w2_0,
                         const float* __restrict__ w1_r, const float* __restrict__ w2_r,
                         unsigned short* __restrict__ wt0, unsigned short* __restrict__ wts) {
  int idx = blockIdx.x * 256 + threadIdx.x;
  const int S0 = HPAD * K0PAD;           // 20480
  const int SW = HPAD * HPAD;            // 409600
  if (idx < S0) {
    int n = idx / K0PAD, k = idx % K0PAD;
    float v = (n < HID && k < IN_FEATS) ? w1_0[(size_t)k * HID + n] : 0.f;
    wt0[idx] = f2bf(v);
    return;
  }
  idx -= S0;
  if (idx >= 9 * SW) return;
  int w = idx / SW, r = idx % SW;
  int n = r / HPAD, k = r % HPAD;
  const float* W;
  if (w == 0) W = w2_0;
  else if (w < 5) W = w1_r + (size_t)(w - 1) * HID * HID;
  else W = w2_r + (size_t)(w - 5) * HID * HID;
  float v = (n < HID && k < HID) ? W[(size_t)k * HID + n] : 0.f;
  wts[(size_t)w * SW + r] = f2bf(v);
}

// biases[10][HPAD] <- {b1_0, b2_0, b1_r[0..3], b2_r[0..3]}
__global__ void k_bias_all(const float* __restrict__ b1_0, const float* __restrict__ b2_0,
                           const float* __restrict__ b1_r, const float* __restrict__ b2_r,
                           float* __restrict__ biases) {
  int idx = blockIdx.x * 256 + threadIdx.x;
  if (idx >= 10 * HPAD) return;
  int w = idx / HPAD, i = idx % HPAD;
  float v = 0.f;
  if (i < HID) {
    if (w == 0) v = b1_0[i];
    else if (w == 1) v = b2_0[i];
    else if (w < 6) v = b1_r[(size_t)(w - 2) * HID + i];
    else v = b2_r[(size_t)(w - 6) * HID + i];
  }
  biases[idx] = v;
}

// x [30000][9] f32 -> xb [30080][32] bf16, zero-padded
__global__ void k_xconv(const float* __restrict__ x, unsigned short* __restrict__ xb) {
  int idx = blockIdx.x * 256 + threadIdx.x;
  if (idx >= MPAD * K0PAD) return;
  int m = idx >> 5, k = idx & 31;
  float v = (m < N_NODES && k < IN_FEATS) ? x[(size_t)m * IN_FEATS + k] : 0.f;
  xb[idx] = f2bf(v);
}

// ---------------- aggregation (bf16): z[i] = h[i] + sum_{e:dst=i} h[src] ----------------

template <int U>
__global__ __launch_bounds__(256) void k_agg_bf16(
    const unsigned int* __restrict__ h, const int* __restrict__ ptr,
    const int* __restrict__ esrc, unsigned int* __restrict__ z, int n_nodes) {
  int wave = threadIdx.x >> 6, lane = threadIdx.x & 63;
  int node = blockIdx.x * 4 + wave;
  if (node >= n_nodes) return;
  int beg = ptr[node], end = ptr[node + 1];
  const unsigned int* hn = h + (size_t)node * U;
  float a0[5], a1[5];
#pragma unroll
  for (int i = 0; i < 5; ++i) {
    int u = lane + i * 64;
    if (u < U) { unsigned int v = hn[u]; a0[i] = bflo(v); a1[i] = bfhi(v); }
    else { a0[i] = 0.f; a1[i] = 0.f; }
  }
  for (int e = beg; e < end; ++e) {
    const unsigned int* hs = h + (size_t)esrc[e] * U;
#pragma unroll
    for (int i = 0; i < 5; ++i) {
      int u = lane + i * 64;
      if (u < U) { unsigned int v = hs[u]; a0[i] += bflo(v); a1[i] += bfhi(v); }
    }
  }
  unsigned int* zn = z + (size_t)node * U;
#pragma unroll
  for (int i = 0; i < 5; ++i) {
    int u = lane + i * 64;
    if (u < U) zn[u] = pack2(a0[i], a1[i]);
  }
}

// ---------------- pool ----------------

__global__ __launch_bounds__(256) void k_pool_bf16(
    const unsigned int* __restrict__ h, const int* __restrict__ gptr,
    float* __restrict__ feats) {
  const int U = HPAD / 2;  // 320
  int wave = threadIdx.x >> 6, lane = threadIdx.x & 63;
  int g = blockIdx.x * 4 + wave;
  int beg = gptr[g], end = gptr[g + 1];
  float a0[5] = {0.f, 0.f, 0.f, 0.f, 0.f}, a1[5] = {0.f, 0.f, 0.f, 0.f, 0.f};
  for (int i = beg; i < end; ++i) {
    const unsigned int* hi = h + (size_t)i * U;
#pragma unroll
    for (int j = 0; j < 5; ++j) {
      unsigned int v = hi[lane + j * 64];
      a0[j] += bflo(v); a1[j] += bfhi(v);
    }
  }
  float* fg = feats + (size_t)g * HPAD;
#pragma unroll
  for (int j = 0; j < 5; ++j) {
    int u = lane + j * 64;
    fg[2 * u] = a0[j];
    fg[2 * u + 1] = a1[j];
  }
}

// ---------------- bf16 MFMA GEMM (m97 structure) ----------------

__global__ __launch_bounds__(256) void k_mgemm(
    const unsigned short* __restrict__ A, const unsigned short* __restrict__ Bt,
    const float* __restrict__ bias, unsigned short* __restrict__ C,
    int lda, int ldb, int K, int relu) {
  __shared__ unsigned short As[128 * 32];
  __shared__ unsigned short Bs[128 * 32];
  int t = threadIdx.x;
  int lane = t & 63, wave = t >> 6;
  int m0 = blockIdx.x * 128, n0 = blockIdx.y * 128;
  int wm = (wave >> 1) * 64, wn = (wave & 1) * 64;

  f32x4 acc[4][4] = {};

  int off0 = t * 8, off1 = t * 8 + 2048;
  int rm0 = off0 >> 5, rk0 = off0 & 31;
  int rm1 = off1 >> 5, rk1 = off1 & 31;

  for (int k0 = 0; k0 < K; k0 += 32) {
    __builtin_amdgcn_global_load_lds(
        (const __attribute__((address_space(1))) unsigned int*)(A + (size_t)(m0 + rm0) * lda + k0 + rk0),
        (__attribute__((address_space(3))) unsigned int*)(As + off0), 16, 0, 0);
    __builtin_amdgcn_global_load_lds(
        (const __attribute__((address_space(1))) unsigned int*)(A + (size_t)(m0 + rm1) * lda + k0 + rk1),
        (__attribute__((address_space(3))) unsigned int*)(As + off1), 16, 0, 0);
    __builtin_amdgcn_global_load_lds(
        (const __attribute__((address_space(1))) unsigned int*)(Bt + (size_t)(n0 + rm0) * ldb + k0 + rk0),
        (__attribute__((address_space(3))) unsigned int*)(Bs + off0), 16, 0, 0);
    __builtin_amdgcn_global_load_lds(
        (const __attribute__((address_space(1))) unsigned int*)(Bt + (size_t)(n0 + rm1) * ldb + k0 + rk1),
        (__attribute__((address_space(3))) unsigned int*)(Bs + off1), 16, 0, 0);
    __syncthreads();

    int kk = (lane >> 4) * 8;
    int ra = wm + (lane & 15);
    int rb = wn + (lane & 15);
    bf16x8 a[4], b[4];
#pragma unroll
    for (int i = 0; i < 4; ++i)
      a[i] = *(const bf16x8*)(As + (ra + i * 16) * 32 + kk);
#pragma unroll
    for (int j = 0; j < 4; ++j)
      b[j] = *(const bf16x8*)(Bs + (rb + j * 16) * 32 + kk);
#pragma unroll
    for (int i = 0; i < 4; ++i)
#pragma unroll
      for (int j = 0; j < 4; ++j)
        acc[i][j] = __builtin_amdgcn_mfma_f32_16x16x32_bf16(a[i], b[j], acc[i][j], 0, 0, 0);
    __syncthreads();
  }

  int col = lane & 15, r4 = (lane >> 4) * 4;
#pragma unroll
  for (int j = 0; j < 4; ++j) {
    int n = n0 + wn + j * 16 + col;
    float bv = bias[n];
#pragma unroll
    for (int i = 0; i < 4; ++i) {
      int mb = m0 + wm + i * 16 + r4;
#pragma unroll
      for (int r = 0; r < 4; ++r) {
        float v = acc[i][j][r] + bv;
        if (relu) v = fmaxf(v, 0.f);
        C[(size_t)(mb + r) * HPAD + n] = f2bf(v);
      }
    }
  }
}

// ---------------- fused classifier: block per graph ----------------

__global__ __launch_bounds__(256) void k_classifier(
    const float* __restrict__ feats,                       // [512][HPAD]
    const float* __restrict__ cw1, const float* __restrict__ cb1,  // [600][256],[256]
    const float* __restrict__ cw2, const float* __restrict__ cb2,  // [256][256],[256]
    const float* __restrict__ cw3, const float* __restrict__ cb3,  // [256][128],[128]
    float* __restrict__ out) {                             // [512][128]
  __shared__ float f[HID];
  __shared__ float z1[256];
  __shared__ float z2[256];
  int g = blockIdx.x;
  int t = threadIdx.x;
  for (int i = t; i < HID; i += 256) f[i] = feats[(size_t)g * HPAD + i];
  __syncthreads();
  float acc = cb1[t];
#pragma unroll 8
  for (int k = 0; k < HID; ++k) acc += f[k] * cw1[(size_t)k * 256 + t];
  z1[t] = fmaxf(acc, 0.f);
  __syncthreads();
  acc = cb2[t];
#pragma unroll 8
  for (int k = 0; k < 256; ++k) acc += z1[k] * cw2[(size_t)k * 256 + t];
  z2[t] = fmaxf(acc, 0.f);
  __syncthreads();
  if (t < NUM_TASKS) {
    acc = cb3[t];
#pragma unroll 8
    for (int k = 0; k < 256; ++k) acc += z2[k] * cw3[(size_t)k * NUM_TASKS + t];
    out[(size_t)g * NUM_TASKS + t] = acc;
  }
}

// ---------------- host ----------------

extern "C" void kernel_launch(void* const* d_in, const int* in_sizes, int n_in,
                              void* d_out, int out_size, void* d_ws, size_t ws_size,
                              hipStream_t stream) {
  const float* x      = (const float*)d_in[0];
  const int*   ei     = (const int*)d_in[1];
  const int*   batch  = (const int*)d_in[2];
  const float* w1_0   = (const float*)d_in[3];
  const float* b1_0   = (const float*)d_in[4];
  const float* w2_0   = (const float*)d_in[5];
  const float* b2_0   = (const float*)d_in[6];
  const float* w1_r   = (const float*)d_in[7];
  const float* b1_r   = (const float*)d_in[8];
  const float* w2_r   = (const float*)d_in[9];
  const float* b2_r   = (const float*)d_in[10];
  const float* cw1    = (const float*)d_in[11];
  const float* cb1    = (const float*)d_in[12];
  const float* cw2    = (const float*)d_in[13];
  const float* cb2    = (const float*)d_in[14];
  const float* cw3    = (const float*)d_in[15];
  const float* cb3    = (const float*)d_in[16];
  float* out = (float*)d_out;

  const int* e_src = ei;
  const int* e_dst = ei + N_EDGES;

  const size_t HBUF = (size_t)MPAD * HPAD;
  const size_t ZBUF = (size_t)MPAD * K0PAD;
  const size_t WT   = (size_t)HPAD * HPAD;

  unsigned short* hA  = (unsigned short*)d_ws;
  unsigned short* hB  = hA + HBUF;
  unsigned short* hC  = hB + HBUF;
  unsigned short* z0  = hC + HBUF;
  unsigned short* xb  = z0 + ZBUF;
  unsigned short* wt0 = xb + ZBUF;
  unsigned short* wts = wt0 + (size_t)HPAD * K0PAD;
  float* biases = (float*)(wts + 9 * WT);
  float* feats  = biases + 10 * HPAD;
  int* row_ptr  = (int*)(feats + (size_t)NUM_GRAPHS * HPAD);
  int* counts   = row_ptr + (N_NODES + 1);
  int* edge_src = counts + N_NODES;
  int* gptr     = edge_src + N_EDGES;
  int* gcnt     = gptr + (NUM_GRAPHS + 1);

  // ---- fused conversions ----
  {
    int total = HPAD * K0PAD + 9 * HPAD * HPAD;
    k_wt_all<<<(total + 255) / 256, 256, 0, stream>>>(w1_0, w2_0, w1_r, w2_r, wt0, wts);
  }
  k_bias_all<<<(10 * HPAD + 255) / 256, 256, 0, stream>>>(b1_0, b2_0, b1_r, b2_r, biases);
  k_xconv<<<(MPAD * K0PAD + 255) / 256, 256, 0, stream>>>(x, xb);

  // ---- CSR by destination ----
  hipMemsetAsync(counts, 0, N_NODES * sizeof(int), stream);
  k_hist<<<(N_EDGES + 255) / 256, 256, 0, stream>>>(e_dst, counts, N_EDGES);
  k_exscan<<<1, 1024, 0, stream>>>(counts, row_ptr, N_NODES);
  k_copy_int<<<(N_NODES + 255) / 256, 256, 0, stream>>>(row_ptr, counts, N_NODES);
  k_scatter<<<(N_EDGES + 255) / 256, 256, 0, stream>>>(e_src, e_dst, counts, edge_src, N_EDGES);

  hipMemsetAsync(gcnt, 0, NUM_GRAPHS * sizeof(int), stream);
  k_hist<<<(N_NODES + 255) / 256, 256, 0, stream>>>(batch, gcnt, N_NODES);
  k_exscan<<<1, 1024, 0, stream>>>(gcnt, gptr, NUM_GRAPHS);

  dim3 ggrid(MPAD / 128, HPAD / 128);  // 235 x 5

  // ---- layer 0 ----
  k_agg_bf16<K0PAD / 2><<<(N_NODES + 3) / 4, 256, 0, stream>>>(
      (const unsigned int*)xb, row_ptr, edge_src, (unsigned int*)z0, N_NODES);
  k_mgemm<<<ggrid, 256, 0, stream>>>(z0, wt0, biases + 0 * HPAD, hC, K0PAD, K0PAD, K0PAD, 1);
  k_mgemm<<<ggrid, 256, 0, stream>>>(hC, wts, biases + 1 * HPAD, hA, HPAD, HPAD, HPAD, 1);

  // ---- layers 1..4 ----
  unsigned short* h = hA;
  unsigned short* z = hB;
  unsigned short* tb = hC;
  for (int i = 0; i < 4; ++i) {
    k_agg_bf16<HPAD / 2><<<(N_NODES + 3) / 4, 256, 0, stream>>>(
        (const unsigned int*)h, row_ptr, edge_src, (unsigned int*)z, N_NODES);
    k_mgemm<<<ggrid, 256, 0, stream>>>(z, wts + (1 + (size_t)i) * WT, biases + (2 + i) * HPAD, tb,
                                       HPAD, HPAD, HPAD, 1);
    k_mgemm<<<ggrid, 256, 0, stream>>>(tb, wts + (5 + (size_t)i) * WT, biases + (6 + i) * HPAD, z,
                                       HPAD, HPAD, HPAD, (i < 3) ? 1 : 0);
    unsigned short* tmp = h; h = z; z = tmp;
  }

  // ---- pool + fused classifier ----
  k_pool_bf16<<<NUM_GRAPHS / 4, 256, 0, stream>>>((const unsigned int*)h, gptr, feats);
  k_classifier<<<NUM_GRAPHS, 256, 0, stream>>>(feats, cw1, cb1, cw2, cb2, cw3, cb3, out);
}

// Round 4
// 823.225 us; speedup vs baseline: 8.6573x; 1.1248x over previous
//
#include <hip/hip_runtime.h>

#define N_NODES 30000
#define N_EDGES 300000
#define NUM_GRAPHS 512
#define HID 600
#define IN_FEATS 9
#define NUM_TASKS 128

#define MPAD 30080          // 235 * 128
#define HPAD 640            // 600 padded
#define K0PAD 32            // layer-0 K pad

typedef __attribute__((ext_vector_type(4))) float f32x4;
typedef __attribute__((ext_vector_type(8))) short bf16x8;

// ---------------- bf16 helpers ----------------

__device__ __forceinline__ float bflo(unsigned int v) {
  union { unsigned int u; float f; } c; c.u = v << 16; return c.f;
}
__device__ __forceinline__ float bfhi(unsigned int v) {
  union { unsigned int u; float f; } c; c.u = v & 0xffff0000u; return c.f;
}
__device__ __forceinline__ unsigned short f2bf(float f) {
  union { float f; unsigned int u; } c; c.f = f;
  unsigned int u = c.u;
  return (unsigned short)((u + 0x7fffu + ((u >> 16) & 1u)) >> 16);
}
__device__ __forceinline__ unsigned int pack2(float a, float b) {
  return (unsigned int)f2bf(a) | ((unsigned int)f2bf(b) << 16);
}

// ---------------- CSR build ----------------

__global__ void k_hist(const int* __restrict__ keys, int* __restrict__ counts, int n) {
  int i = blockIdx.x * blockDim.x + threadIdx.x;
  if (i < n) atomicAdd(&counts[keys[i]], 1);
}

__global__ __launch_bounds__(1024) void k_exscan(const int* __restrict__ in,
                                                 int* __restrict__ out, int n) {
  __shared__ int buf[1024];
  int tid = threadIdx.x;
  int CH = (n + 1023) / 1024;
  int base = tid * CH;
  int s = 0;
  for (int j = 0; j < CH; ++j) {
    int i = base + j;
    if (i < n) s += in[i];
  }
  buf[tid] = s;
  __syncthreads();
  for (int off = 1; off < 1024; off <<= 1) {
    int t = (tid >= off) ? buf[tid - off] : 0;
    __syncthreads();
    buf[tid] += t;
    __syncthreads();
  }
  int pre = (tid == 0) ? 0 : buf[tid - 1];
  for (int j = 0; j < CH; ++j) {
    int i = base + j;
    if (i <= n) out[i] = pre;
    if (i < n) pre += in[i];
  }
}

__global__ void k_copy_int(const int* __restrict__ in, int* __restrict__ out, int n) {
  int i = blockIdx.x * blockDim.x + threadIdx.x;
  if (i < n) out[i] = in[i];
}

__global__ void k_scatter(const int* __restrict__ src, const int* __restrict__ dst,
                          int* __restrict__ cursor, int* __restrict__ edge_src, int E) {
  int e = blockIdx.x * blockDim.x + threadIdx.x;
  if (e < E) {
    int pos = atomicAdd(&cursor[dst[e]], 1);
    edge_src[pos] = src[e];
  }
}

// ---------------- fused conversions ----------------

__global__ void k_wt_all(const float* __restrict__ w1_0, const float* __restrict__ w2_0,
                         const float* __restrict__ w1_r, const float* __restrict__ w2_r,
                         unsigned short* __restrict__ wt0, unsigned short* __restrict__ wts) {
  int idx = blockIdx.x * 256 + threadIdx.x;
  const int S0 = HPAD * K0PAD;
  const int SW = HPAD * HPAD;
  if (idx < S0) {
    int n = idx / K0PAD, k = idx % K0PAD;
    float v = (n < HID && k < IN_FEATS) ? w1_0[(size_t)k * HID + n] : 0.f;
    wt0[idx] = f2bf(v);
    return;
  }
  idx -= S0;
  if (idx >= 9 * SW) return;
  int w = idx / SW, r = idx % SW;
  int n = r / HPAD, k = r % HPAD;
  const float* W;
  if (w == 0) W = w2_0;
  else if (w < 5) W = w1_r + (size_t)(w - 1) * HID * HID;
  else W = w2_r + (size_t)(w - 5) * HID * HID;
  float v = (n < HID && k < HID) ? W[(size_t)k * HID + n] : 0.f;
  wts[(size_t)w * SW + r] = f2bf(v);
}

__global__ void k_bias_all(const float* __restrict__ b1_0, const float* __restrict__ b2_0,
                           const float* __restrict__ b1_r, const float* __restrict__ b2_r,
                           float* __restrict__ biases) {
  int idx = blockIdx.x * 256 + threadIdx.x;
  if (idx >= 10 * HPAD) return;
  int w = idx / HPAD, i = idx % HPAD;
  float v = 0.f;
  if (i < HID) {
    if (w == 0) v = b1_0[i];
    else if (w == 1) v = b2_0[i];
    else if (w < 6) v = b1_r[(size_t)(w - 2) * HID + i];
    else v = b2_r[(size_t)(w - 6) * HID + i];
  }
  biases[idx] = v;
}

__global__ void k_xconv(const float* __restrict__ x, unsigned short* __restrict__ xb) {
  int idx = blockIdx.x * 256 + threadIdx.x;
  if (idx >= MPAD * K0PAD) return;
  int m = idx >> 5, k = idx & 31;
  float v = (m < N_NODES && k < IN_FEATS) ? x[(size_t)m * IN_FEATS + k] : 0.f;
  xb[idx] = f2bf(v);
}

// ---------------- aggregation (bf16), edge-loop unrolled x2 ----------------

template <int U>
__global__ __launch_bounds__(256) void k_agg_bf16(
    const unsigned int* __restrict__ h, const int* __restrict__ ptr,
    const int* __restrict__ esrc, unsigned int* __restrict__ z, int n_nodes) {
  int wave = threadIdx.x >> 6, lane = threadIdx.x & 63;
  int node = blockIdx.x * 4 + wave;
  if (node >= n_nodes) return;
  int beg = ptr[node], end = ptr[node + 1];
  const unsigned int* hn = h + (size_t)node * U;
  float a0[5], a1[5];
#pragma unroll
  for (int i = 0; i < 5; ++i) {
    int u = lane + i * 64;
    if (u < U) { unsigned int v = hn[u]; a0[i] = bflo(v); a1[i] = bfhi(v); }
    else { a0[i] = 0.f; a1[i] = 0.f; }
  }
  int e = beg;
  for (; e + 2 <= end; e += 2) {
    const unsigned int* p0 = h + (size_t)esrc[e] * U;
    const unsigned int* p1 = h + (size_t)esrc[e + 1] * U;
    unsigned int v0[5], v1[5];
#pragma unroll
    for (int i = 0; i < 5; ++i) {
      int u = lane + i * 64;
      if (u < U) { v0[i] = p0[u]; v1[i] = p1[u]; }
      else { v0[i] = 0; v1[i] = 0; }
    }
#pragma unroll
    for (int i = 0; i < 5; ++i) {
      a0[i] += bflo(v0[i]) + bflo(v1[i]);
      a1[i] += bfhi(v0[i]) + bfhi(v1[i]);
    }
  }
  if (e < end) {
    const unsigned int* p0 = h + (size_t)esrc[e] * U;
#pragma unroll
    for (int i = 0; i < 5; ++i) {
      int u = lane + i * 64;
      if (u < U) { unsigned int v = p0[u]; a0[i] += bflo(v); a1[i] += bfhi(v); }
    }
  }
  unsigned int* zn = z + (size_t)node * U;
#pragma unroll
  for (int i = 0; i < 5; ++i) {
    int u = lane + i * 64;
    if (u < U) zn[u] = pack2(a0[i], a1[i]);
  }
}

// ---------------- pool: block per graph, 4-wave row split ----------------

__global__ __launch_bounds__(256) void k_pool_bf16(
    const unsigned int* __restrict__ h, const int* __restrict__ gptr,
    float* __restrict__ feats) {
  const int U = HPAD / 2;  // 320
  __shared__ float red[4][HPAD];
  int t = threadIdx.x;
  int wave = t >> 6, lane = t & 63;
  int g = blockIdx.x;
  int beg = gptr[g], end = gptr[g + 1];
  float a0[5] = {0.f, 0.f, 0.f, 0.f, 0.f}, a1[5] = {0.f, 0.f, 0.f, 0.f, 0.f};
  for (int i = beg + wave; i < end; i += 4) {
    const unsigned int* hi = h + (size_t)i * U;
#pragma unroll
    for (int j = 0; j < 5; ++j) {
      unsigned int v = hi[lane + j * 64];
      a0[j] += bflo(v); a1[j] += bfhi(v);
    }
  }
#pragma unroll
  for (int j = 0; j < 5; ++j) {
    int u = lane + j * 64;
    red[wave][2 * u] = a0[j];
    red[wave][2 * u + 1] = a1[j];
  }
  __syncthreads();
  float* fg = feats + (size_t)g * HPAD;
  for (int c = t; c < HPAD; c += 256)
    fg[c] = red[0][c] + red[1][c] + red[2][c] + red[3][c];
}

// ---------------- bf16 MFMA GEMM (m97 structure, XCD-chunked 1D grid) ----------------

__global__ __launch_bounds__(256) void k_mgemm(
    const unsigned short* __restrict__ A, const unsigned short* __restrict__ Bt,
    const float* __restrict__ bias, unsigned short* __restrict__ C,
    int lda, int ldb, int ldc, int K, int relu, int gy) {
  // bijective XCD-chunked swizzle (m204)
  int G = gridDim.x;
  int orig = blockIdx.x;
  int q = G >> 3, r = G & 7;
  int xcd = orig & 7, local = orig >> 3;
  int wgid = (xcd < r ? xcd * (q + 1) : r * (q + 1) + (xcd - r) * q) + local;
  int n0 = (wgid % gy) * 128;
  int m0 = (wgid / gy) * 128;

  __shared__ unsigned short As[128 * 32];
  __shared__ unsigned short Bs[128 * 32];
  int t = threadIdx.x;
  int lane = t & 63, wave = t >> 6;
  int wm = (wave >> 1) * 64, wn = (wave & 1) * 64;

  f32x4 acc[4][4] = {};

  int off0 = t * 8, off1 = t * 8 + 2048;
  int rm0 = off0 >> 5, rk0 = off0 & 31;
  int rm1 = off1 >> 5, rk1 = off1 & 31;

  for (int k0 = 0; k0 < K; k0 += 32) {
    __builtin_amdgcn_global_load_lds(
        (const __attribute__((address_space(1))) unsigned int*)(A + (size_t)(m0 + rm0) * lda + k0 + rk0),
        (__attribute__((address_space(3))) unsigned int*)(As + off0), 16, 0, 0);
    __builtin_amdgcn_global_load_lds(
        (const __attribute__((address_space(1))) unsigned int*)(A + (size_t)(m0 + rm1) * lda + k0 + rk1),
        (__attribute__((address_space(3))) unsigned int*)(As + off1), 16, 0, 0);
    __builtin_amdgcn_global_load_lds(
        (const __attribute__((address_space(1))) unsigned int*)(Bt + (size_t)(n0 + rm0) * ldb + k0 + rk0),
        (__attribute__((address_space(3))) unsigned int*)(Bs + off0), 16, 0, 0);
    __builtin_amdgcn_global_load_lds(
        (const __attribute__((address_space(1))) unsigned int*)(Bt + (size_t)(n0 + rm1) * ldb + k0 + rk1),
        (__attribute__((address_space(3))) unsigned int*)(Bs + off1), 16, 0, 0);
    __syncthreads();

    int kk = (lane >> 4) * 8;
    int ra = wm + (lane & 15);
    int rb = wn + (lane & 15);
    bf16x8 a[4], b[4];
#pragma unroll
    for (int i = 0; i < 4; ++i)
      a[i] = *(const bf16x8*)(As + (ra + i * 16) * 32 + kk);
#pragma unroll
    for (int j = 0; j < 4; ++j)
      b[j] = *(const bf16x8*)(Bs + (rb + j * 16) * 32 + kk);
#pragma unroll
    for (int i = 0; i < 4; ++i)
#pragma unroll
      for (int j = 0; j < 4; ++j)
        acc[i][j] = __builtin_amdgcn_mfma_f32_16x16x32_bf16(a[i], b[j], acc[i][j], 0, 0, 0);
    __syncthreads();
  }

  int col = lane & 15, r4 = (lane >> 4) * 4;
#pragma unroll
  for (int j = 0; j < 4; ++j) {
    int n = n0 + wn + j * 16 + col;
    float bv = bias[n];
#pragma unroll
    for (int i = 0; i < 4; ++i) {
      int mb = m0 + wm + i * 16 + r4;
#pragma unroll
      for (int rr = 0; rr < 4; ++rr) {
        float v = acc[i][j][rr] + bv;
        if (relu) v = fmaxf(v, 0.f);
        C[(size_t)(mb + rr) * ldc + n] = f2bf(v);
      }
    }
  }
}

// ---------------- fused classifier: block per graph, split-K across waves ----------------

__global__ __launch_bounds__(256) void k_classifier(
    const float* __restrict__ feats,
    const float* __restrict__ cw1, const float* __restrict__ cb1,
    const float* __restrict__ cw2, const float* __restrict__ cb2,
    const float* __restrict__ cw3, const float* __restrict__ cb3,
    float* __restrict__ out) {
  __shared__ float f[HID];
  __shared__ float red[4][256];
  __shared__ float z1[256];
  __shared__ float z2[256];
  int g = blockIdx.x;
  int t = threadIdx.x;
  int wave = t >> 6, lane = t & 63;
  for (int i = t; i < HID; i += 256) f[i] = feats[(size_t)g * HPAD + i];
  __syncthreads();

  // layer 1: K=600 -> 150 per wave, 4 cols per lane
  {
    float acc[4] = {0.f, 0.f, 0.f, 0.f};
    int k0 = wave * 150, k1 = k0 + 150;
    for (int k = k0; k < k1; ++k) {
      float fv = f[k];
      const float* row = cw1 + (size_t)k * 256;
#pragma unroll
      for (int j = 0; j < 4; ++j) acc[j] += fv * row[lane + j * 64];
    }
#pragma unroll
    for (int j = 0; j < 4; ++j) red[wave][lane + j * 64] = acc[j];
  }
  __syncthreads();
  z1[t] = fmaxf(red[0][t] + red[1][t] + red[2][t] + red[3][t] + cb1[t], 0.f);
  __syncthreads();

  // layer 2: K=256 -> 64 per wave
  {
    float acc[4] = {0.f, 0.f, 0.f, 0.f};
    int k0 = wave * 64, k1 = k0 + 64;
    for (int k = k0; k < k1; ++k) {
      float zv = z1[k];
      const float* row = cw2 + (size_t)k * 256;
#pragma unroll
      for (int j = 0; j < 4; ++j) acc[j] += zv * row[lane + j * 64];
    }
    __syncthreads();  // ensure all reads of red (layer1) done before overwrite
#pragma unroll
    for (int j = 0; j < 4; ++j) red[wave][lane + j * 64] = acc[j];
  }
  __syncthreads();
  z2[t] = fmaxf(red[0][t] + red[1][t] + red[2][t] + red[3][t] + cb2[t], 0.f);
  __syncthreads();

  // layer 3: K=256 -> 64 per wave, 128 outputs -> 2 cols per lane
  {
    float a0 = 0.f, a1 = 0.f;
    int k0 = wave * 64, k1 = k0 + 64;
    for (int k = k0; k < k1; ++k) {
      float zv = z2[k];
      const float* row = cw3 + (size_t)k * NUM_TASKS;
      a0 += zv * row[lane];
      a1 += zv * row[lane + 64];
    }
    __syncthreads();
    red[wave][lane] = a0;
    red[wave][lane + 64] = a1;
  }
  __syncthreads();
  if (t < NUM_TASKS)
    out[(size_t)g * NUM_TASKS + t] = red[0][t] + red[1][t] + red[2][t] + red[3][t] + cb3[t];
}

// ---------------- host ----------------

extern "C" void kernel_launch(void* const* d_in, const int* in_sizes, int n_in,
                              void* d_out, int out_size, void* d_ws, size_t ws_size,
                              hipStream_t stream) {
  const float* x      = (const float*)d_in[0];
  const int*   ei     = (const int*)d_in[1];
  const int*   batch  = (const int*)d_in[2];
  const float* w1_0   = (const float*)d_in[3];
  const float* b1_0   = (const float*)d_in[4];
  const float* w2_0   = (const float*)d_in[5];
  const float* b2_0   = (const float*)d_in[6];
  const float* w1_r   = (const float*)d_in[7];
  const float* b1_r   = (const float*)d_in[8];
  const float* w2_r   = (const float*)d_in[9];
  const float* b2_r   = (const float*)d_in[10];
  const float* cw1    = (const float*)d_in[11];
  const float* cb1    = (const float*)d_in[12];
  const float* cw2    = (const float*)d_in[13];
  const float* cb2    = (const float*)d_in[14];
  const float* cw3    = (const float*)d_in[15];
  const float* cb3    = (const float*)d_in[16];
  float* out = (float*)d_out;

  const int* e_src = ei;
  const int* e_dst = ei + N_EDGES;

  const size_t HBUF = (size_t)MPAD * HPAD;
  const size_t ZBUF = (size_t)MPAD * K0PAD;
  const size_t WT   = (size_t)HPAD * HPAD;

  unsigned short* hA  = (unsigned short*)d_ws;
  unsigned short* hB  = hA + HBUF;
  unsigned short* hC  = hB + HBUF;
  unsigned short* z0  = hC + HBUF;
  unsigned short* xb  = z0 + ZBUF;
  unsigned short* wt0 = xb + ZBUF;
  unsigned short* wts = wt0 + (size_t)HPAD * K0PAD;
  float* biases = (float*)(wts + 9 * WT);
  float* feats  = biases + 10 * HPAD;
  int* row_ptr  = (int*)(feats + (size_t)NUM_GRAPHS * HPAD);
  int* counts   = row_ptr + (N_NODES + 1);
  int* edge_src = counts + N_NODES;
  int* gptr     = edge_src + N_EDGES;
  int* gcnt     = gptr + (NUM_GRAPHS + 1);

  // ---- fused conversions ----
  {
    int total = HPAD * K0PAD + 9 * HPAD * HPAD;
    k_wt_all<<<(total + 255) / 256, 256, 0, stream>>>(w1_0, w2_0, w1_r, w2_r, wt0, wts);
  }
  k_bias_all<<<(10 * HPAD + 255) / 256, 256, 0, stream>>>(b1_0, b2_0, b1_r, b2_r, biases);
  k_xconv<<<(MPAD * K0PAD + 255) / 256, 256, 0, stream>>>(x, xb);

  // ---- CSR by destination ----
  hipMemsetAsync(counts, 0, N_NODES * sizeof(int), stream);
  k_hist<<<(N_EDGES + 255) / 256, 256, 0, stream>>>(e_dst, counts, N_EDGES);
  k_exscan<<<1, 1024, 0, stream>>>(counts, row_ptr, N_NODES);
  k_copy_int<<<(N_NODES + 255) / 256, 256, 0, stream>>>(row_ptr, counts, N_NODES);
  k_scatter<<<(N_EDGES + 255) / 256, 256, 0, stream>>>(e_src, e_dst, counts, edge_src, N_EDGES);

  hipMemsetAsync(gcnt, 0, NUM_GRAPHS * sizeof(int), stream);
  k_hist<<<(N_NODES + 255) / 256, 256, 0, stream>>>(batch, gcnt, N_NODES);
  k_exscan<<<1, 1024, 0, stream>>>(gcnt, gptr, NUM_GRAPHS);

  const int G = (MPAD / 128) * (HPAD / 128);  // 1175
  const int GY = HPAD / 128;                  // 5

  // ---- layer 0 ----
  k_agg_bf16<K0PAD / 2><<<(N_NODES + 3) / 4, 256, 0, stream>>>(
      (const unsigned int*)xb, row_ptr, edge_src, (unsigned int*)z0, N_NODES);
  k_mgemm<<<G, 256, 0, stream>>>(z0, wt0, biases + 0 * HPAD, hC, K0PAD, K0PAD, HPAD, K0PAD, 1, GY);
  k_mgemm<<<G, 256, 0, stream>>>(hC, wts, biases + 1 * HPAD, hA, HPAD, HPAD, HPAD, HPAD, 1, GY);

  // ---- layers 1..4 ----
  unsigned short* h = hA;
  unsigned short* z = hB;
  unsigned short* tb = hC;
  for (int i = 0; i < 4; ++i) {
    k_agg_bf16<HPAD / 2><<<(N_NODES + 3) / 4, 256, 0, stream>>>(
        (const unsigned int*)h, row_ptr, edge_src, (unsigned int*)z, N_NODES);
    k_mgemm<<<G, 256, 0, stream>>>(z, wts + (1 + (size_t)i) * WT, biases + (2 + i) * HPAD, tb,
                                   HPAD, HPAD, HPAD, HPAD, 1, GY);
    k_mgemm<<<G, 256, 0, stream>>>(tb, wts + (5 + (size_t)i) * WT, biases + (6 + i) * HPAD, z,
                                   HPAD, HPAD, HPAD, HPAD, (i < 3) ? 1 : 0, GY);
    unsigned short* tmp = h; h = z; z = tmp;
  }

  // ---- pool + fused classifier ----
  k_pool_bf16<<<NUM_GRAPHS, 256, 0, stream>>>((const unsigned int*)h, gptr, feats);
  k_classifier<<<NUM_GRAPHS, 256, 0, stream>>>(feats, cw1, cb1, cw2, cb2, cw3, cb3, out);
}